// Round 8
// baseline (33.261 us; speedup 1.0000x reference)
//
#include <hip/hip_runtime.h>

// HungarianMatcher cost matrix: C[n,m] = 5*L1(boxes) + 2*focal_class - 2*GIoU
// logits [N=16000, NC=256] f32, pred_boxes [N,4] cxcywh f32,
// tgt_labels [M=1600] i32, tgt_boxes [M,4] cxcywh f32, out [N,M] f32.

constexpr float ALPHAc = 0.25f;
constexpr float EPSc   = 1e-8f;

constexpr int NC  = 256;  // classes (== blockDim.x)
constexpr int NT  = 256;  // threads per block
constexpr int RPB = 8;    // rows per block (16000 % 8 == 0 -> 2000 blocks, all full)

typedef float f32x4 __attribute__((ext_vector_type(4)));
typedef float f32x2 __attribute__((ext_vector_type(2)));

struct TBox { float x0, y0, x1, y1, area; };

__device__ __forceinline__ TBox make_box(float4 b) {
    TBox r;
    r.x0 = fmaf(-0.5f, b.z, b.x);
    r.y0 = fmaf(-0.5f, b.w, b.y);
    r.x1 = fmaf( 0.5f, b.z, b.x);
    r.y1 = fmaf( 0.5f, b.w, b.y);
    r.area = b.z * b.w;
    return r;
}

__device__ __forceinline__ const float* fc_base(const float* fc0, int c) {
    c = c < 0 ? 0 : (c > NC - 1 ? NC - 1 : c);
    return fc0 + c;
}

// res = 5*L1 + (2*fc+2) - 2*(inter/uni + uni/carea)
__device__ __forceinline__ float cost_elem(float px0, float py0, float px1, float py1,
                                           float parea, float pw2, float ph2,
                                           const TBox& b, float fcp) {
    const float u0 = b.x0 - px0, u1 = b.x1 - px1;
    const float v0 = b.y0 - py0, v1 = b.y1 - py1;
    const float du = u1 - u0,    dv = v1 - v0;
    const float l1 = fmaf(0.5f, fabsf(u0 + u1), fabsf(du))
                   + fmaf(0.5f, fabsf(v0 + v1), fabsf(dv));
    const float ix0 = fmaxf(px0, b.x0), ix1 = fminf(px1, b.x1);
    const float iy0 = fmaxf(py0, b.y0), iy1 = fminf(py1, b.y1);
    const float iwr = ix1 - ix0, ihr = iy1 - iy0;
    const float inter = fmaxf(iwr, 0.0f) * fmaxf(ihr, 0.0f);
    const float uni   = (parea + b.area) - inter;
    const float cw = (pw2 + du) - iwr;
    const float ch = (ph2 + dv) - ihr;
    const float carea = cw * ch;
    const float num = fmaf(uni, uni, inter * carea);
    const float mm  = num * __builtin_amdgcn_rcpf(uni * carea);
    return fmaf(-2.0f, mm, fmaf(5.0f, l1, fcp));
}

__global__ __launch_bounds__(NT)
void hungarian_cost_kernel(const float* __restrict__ logits,
                           const float* __restrict__ pboxes,
                           const int*   __restrict__ tlabels,
                           const float* __restrict__ tboxes,
                           float*       __restrict__ out,
                           int N, int M)
{
    const int t  = threadIdx.x;
    const int n0 = blockIdx.x * RPB;
    if (n0 >= N) return;
    const int rows = (N - n0 < RPB) ? (N - n0) : RPB;

    __shared__ float fc[RPB][NC];   // 2*focal+2, per row per class
    __shared__ float pp[RPB][8];    // px0,py0,px1,py1,parea,pw2,ph2,pad per row

    // ---- Prologue: focal costs + row params. ONE barrier. ----
#pragma unroll
    for (int r = 0; r < RPB; ++r) {
        if (r < rows) {
            const float x = logits[(size_t)(n0 + r) * NC + t];
            const float p = __builtin_amdgcn_rcpf(1.0f + __expf(-x));
            const float q = 1.0f - p;
            const float pos = ALPHAc * q * q * (-__logf(p + EPSc));
            const float neg = (1.0f - ALPHAc) * p * p * (-__logf(q + EPSc));
            fc[r][t] = fmaf(2.0f, pos - neg, 2.0f);
        }
    }
    if (t < rows) {
        const float4 pb = reinterpret_cast<const float4*>(pboxes)[n0 + t];
        pp[t][0] = fmaf(-0.5f, pb.z, pb.x);
        pp[t][1] = fmaf(-0.5f, pb.w, pb.y);
        pp[t][2] = fmaf( 0.5f, pb.z, pb.x);
        pp[t][3] = fmaf( 0.5f, pb.w, pb.y);
        pp[t][4] = pb.z * pb.w;
        pp[t][5] = pb.z + pb.z;
        pp[t][6] = pb.w + pb.w;
        pp[t][7] = 0.0f;
    }
    __syncthreads();

    const float4* tb4 = reinterpret_cast<const float4*>(tboxes);
    const float*  fc0 = &fc[0][0];

    // m-layout: nA float4 groups, nB float2 groups, scalar tail.
    // M=1600: 256*4 + 256*2 + 64*1.
    const int nA    = (M >> 2) < NT ? (M >> 2) : NT;
    const int baseB = 4 * nA;
    const int nB    = ((M - baseB) >> 1) < NT ? ((M - baseB) >> 1) : NT;
    const int baseC = baseB + 2 * nB;

    if (rows == RPB) {
        // ===================== straight-line fast path =====================
        // All loops fully unrolled, no runtime breaks -> the scheduler can
        // batch ds_reads under counted lgkmcnt and pipeline VALU over stores.

        // ---- Phase A: 4 targets/thread, float4 stores. ----
        if (t < nA) {
            const int4 c4 = reinterpret_cast<const int4*>(tlabels)[t];
            const TBox b0 = make_box(tb4[4 * t + 0]);
            const TBox b1 = make_box(tb4[4 * t + 1]);
            const TBox b2 = make_box(tb4[4 * t + 2]);
            const TBox b3 = make_box(tb4[4 * t + 3]);
            const float* g0 = fc_base(fc0, c4.x);
            const float* g1 = fc_base(fc0, c4.y);
            const float* g2 = fc_base(fc0, c4.z);
            const float* g3 = fc_base(fc0, c4.w);
            float fA[RPB][4];               // statically indexed -> registers
#pragma unroll
            for (int r = 0; r < RPB; ++r) { // 32 ds_read_b32, all issued up-front
                fA[r][0] = g0[r * NC];
                fA[r][1] = g1[r * NC];
                fA[r][2] = g2[r * NC];
                fA[r][3] = g3[r * NC];
            }
#pragma unroll
            for (int r = 0; r < RPB; ++r) {
                const float4 p0 = *reinterpret_cast<const float4*>(&pp[r][0]);
                const float4 p1 = *reinterpret_cast<const float4*>(&pp[r][4]);
                f32x4 res;
                res.x = cost_elem(p0.x, p0.y, p0.z, p0.w, p1.x, p1.y, p1.z, b0, fA[r][0]);
                res.y = cost_elem(p0.x, p0.y, p0.z, p0.w, p1.x, p1.y, p1.z, b1, fA[r][1]);
                res.z = cost_elem(p0.x, p0.y, p0.z, p0.w, p1.x, p1.y, p1.z, b2, fA[r][2]);
                res.w = cost_elem(p0.x, p0.y, p0.z, p0.w, p1.x, p1.y, p1.z, b3, fA[r][3]);
                float* orow = out + (size_t)(n0 + r) * M;
                __builtin_nontemporal_store(res, reinterpret_cast<f32x4*>(orow) + t);
            }
        }

        // ---- Phase B: 2 targets/thread, float2 stores. ----
        if (t < nB) {
            const int2 c2 = reinterpret_cast<const int2*>(tlabels + baseB)[t];
            const TBox b0 = make_box(tb4[baseB + 2 * t + 0]);
            const TBox b1 = make_box(tb4[baseB + 2 * t + 1]);
            const float* g0 = fc_base(fc0, c2.x);
            const float* g1 = fc_base(fc0, c2.y);
            float fB[RPB][2];
#pragma unroll
            for (int r = 0; r < RPB; ++r) {
                fB[r][0] = g0[r * NC];
                fB[r][1] = g1[r * NC];
            }
#pragma unroll
            for (int r = 0; r < RPB; ++r) {
                const float4 p0 = *reinterpret_cast<const float4*>(&pp[r][0]);
                const float4 p1 = *reinterpret_cast<const float4*>(&pp[r][4]);
                f32x2 res;
                res.x = cost_elem(p0.x, p0.y, p0.z, p0.w, p1.x, p1.y, p1.z, b0, fB[r][0]);
                res.y = cost_elem(p0.x, p0.y, p0.z, p0.w, p1.x, p1.y, p1.z, b1, fB[r][1]);
                float* orow = out + (size_t)(n0 + r) * M + baseB;
                __builtin_nontemporal_store(res, reinterpret_cast<f32x2*>(orow) + t);
            }
        }

        // ---- Phase C: scalar tail (64 lanes for M=1600). ----
        if (baseC + t < M) {
            const int e = baseC + t;
            const TBox b = make_box(tb4[e]);
            const float* g = fc_base(fc0, tlabels[e]);
            float fC[RPB];
#pragma unroll
            for (int r = 0; r < RPB; ++r) fC[r] = g[r * NC];
#pragma unroll
            for (int r = 0; r < RPB; ++r) {
                const float4 p0 = *reinterpret_cast<const float4*>(&pp[r][0]);
                const float4 p1 = *reinterpret_cast<const float4*>(&pp[r][4]);
                const float v = cost_elem(p0.x, p0.y, p0.z, p0.w, p1.x, p1.y, p1.z, b, fC[r]);
                __builtin_nontemporal_store(v, out + (size_t)(n0 + r) * M + e);
            }
        }
        // Handle any extra tail beyond one stride (not hit for M=1600).
        for (int e = baseC + NT + t; e < M; e += NT) {
            const TBox b = make_box(tb4[e]);
            const float* g = fc_base(fc0, tlabels[e]);
#pragma unroll
            for (int r = 0; r < RPB; ++r) {
                const float4 p0 = *reinterpret_cast<const float4*>(&pp[r][0]);
                const float4 p1 = *reinterpret_cast<const float4*>(&pp[r][4]);
                const float v = cost_elem(p0.x, p0.y, p0.z, p0.w, p1.x, p1.y, p1.z, b, g[r * NC]);
                __builtin_nontemporal_store(v, out + (size_t)(n0 + r) * M + e);
            }
        }
    } else {
        // ===================== generic fallback (never hit for N=16000) =====
        for (int r = 0; r < rows; ++r) {
            const float4 p0 = *reinterpret_cast<const float4*>(&pp[r][0]);
            const float4 p1 = *reinterpret_cast<const float4*>(&pp[r][4]);
            for (int e = t; e < M; e += NT) {
                const TBox b = make_box(tb4[e]);
                const float f = *fc_base(fc0 + r * NC, tlabels[e]);
                out[(size_t)(n0 + r) * M + e] =
                    cost_elem(p0.x, p0.y, p0.z, p0.w, p1.x, p1.y, p1.z, b, f);
            }
        }
    }
}

extern "C" void kernel_launch(void* const* d_in, const int* in_sizes, int n_in,
                              void* d_out, int out_size, void* d_ws, size_t ws_size,
                              hipStream_t stream) {
    const float* logits  = (const float*)d_in[0];   // [16,1000,256] f32
    const float* pboxes  = (const float*)d_in[1];   // [16,1000,4]  f32
    const int*   tlabels = (const int*)d_in[2];     // [1600] i32
    const float* tboxes  = (const float*)d_in[3];   // [1600,4] f32

    float* out = (float*)d_out;

    const int N = in_sizes[1] / 4;   // 16000 pred rows
    const int M = in_sizes[2];       // 1600 targets

    const int nblocks = (N + RPB - 1) / RPB;   // 2000
    hipLaunchKernelGGL(hungarian_cost_kernel, dim3(nblocks), dim3(NT), 0, stream,
                       logits, pboxes, tlabels, tboxes, out, N, M);
}